// Round 21
// baseline (396.152 us; speedup 1.0000x reference)
//
#include <hip/hip_runtime.h>

#define B_N    1024
#define F_DIMC 768
#define M_DIM  512
#define C_N    100
#define KSTEP  32
#define NSTEP  (F_DIMC / KSTEP)   // 24 k-steps
#define NGEMM  512                // 32 row-tiles x 16 col-tiles
#define NIDX   25                 // fallback: 25 blocks x 4 waves
#define GRID_N 512                // cooperative blocks (2/CU guaranteed)
#define NUNITS (17 * C_N)         // 1700 phi/mu units

typedef float f32x4 __attribute__((ext_vector_type(4)));
typedef short s16x8 __attribute__((ext_vector_type(8)));

__device__ __forceinline__ unsigned int cvt_pk_bf16(float lo, float hi) {
  unsigned int r;
  asm("v_cvt_pk_bf16_f32 %0, %1, %2" : "=v"(r) : "v"(lo), "v"(hi));
  return r;
}

union SMem {
  struct { int lab[B_N]; int cnt[C_N]; int base[C_N]; } ix;
  struct {
    unsigned short Ah[2][32][40], Al[2][32][40];
    unsigned short Bh[2][32][40], Bl[2][32][40];
    int smp[32];
  } g;
  float F[16][M_DIM];
};

// ---------------------------------------------------------------------------
// gemm unit (R19 body): 32x32 tile (rt,ct), rows indirected via rowmap LDS.
// ---------------------------------------------------------------------------
__device__ __forceinline__ void gemm_unit(
    int rt, int ct, int t, const float* __restrict__ X,
    const float* __restrict__ W, float* __restrict__ feat, SMem& sm) {
  const int bn = ct * 32;
  const bool isX = (t < 128);
  const int xr = t >> 2;
  const int xk = (t & 3) * 8;
  const int uu = isX ? 0 : (t - 128);
  const int wk = (uu >> 3) * 2;
  const int wc = (uu & 7) * 4;

  const int arow = sm.g.smp[xr];  // sample row for this staging thread
  const float* __restrict__ Xp = X + (size_t)arow * F_DIMC + xk;
  const float* __restrict__ Wp = W + (size_t)wk * M_DIM + bn + wc;

  const int lane = t & 63;
  const int wv   = t >> 6;
  const int m0 = (wv & 1) * 16;
  const int n0 = (wv >> 1) * 16;
  const int fr = lane & 15;
  const int fq = (lane >> 4) * 8;

  f32x4 acc = {0.f, 0.f, 0.f, 0.f};

  float4 ra0, ra1, rb0, rb1;
  if (isX) {
    ra0 = *(const float4*)(Xp);
    ra1 = *(const float4*)(Xp + 4);
  } else {
    rb0 = *(const float4*)(Wp);
    rb1 = *(const float4*)(Wp + M_DIM);
  }

  auto STAGE = [&](int buf) {
    if (isX) {
      const float v[8] = {ra0.x, ra0.y, ra0.z, ra0.w,
                          ra1.x, ra1.y, ra1.z, ra1.w};
      unsigned int hu[4], lu[4];
#pragma unroll
      for (int j = 0; j < 4; ++j) {
        hu[j] = cvt_pk_bf16(v[2 * j], v[2 * j + 1]);
        const float l0 = v[2 * j] - __builtin_bit_cast(float, hu[j] << 16);
        const float l1 =
            v[2 * j + 1] - __builtin_bit_cast(float, hu[j] & 0xffff0000u);
        lu[j] = cvt_pk_bf16(l0, l1);
      }
      *(uint4*)&sm.g.Ah[buf][xr][xk] = make_uint4(hu[0], hu[1], hu[2], hu[3]);
      *(uint4*)&sm.g.Al[buf][xr][xk] = make_uint4(lu[0], lu[1], lu[2], lu[3]);
    } else {
      const float a[4] = {rb0.x, rb0.y, rb0.z, rb0.w};
      const float d[4] = {rb1.x, rb1.y, rb1.z, rb1.w};
#pragma unroll
      for (int i = 0; i < 4; ++i) {
        const unsigned int h = cvt_pk_bf16(a[i], d[i]);
        const float la = a[i] - __builtin_bit_cast(float, h << 16);
        const float ld = d[i] - __builtin_bit_cast(float, h & 0xffff0000u);
        const unsigned int l = cvt_pk_bf16(la, ld);
        *(unsigned int*)&sm.g.Bh[buf][wc + i][wk] = h;
        *(unsigned int*)&sm.g.Bl[buf][wc + i][wk] = l;
      }
    }
  };

  STAGE(0);
  __syncthreads();

  for (int it = 0; it < NSTEP; ++it) {
    const int cur = it & 1;
    if (it + 1 < NSTEP) {
      const int k0 = (it + 1) * KSTEP;
      if (isX) {
        ra0 = *(const float4*)(Xp + k0);
        ra1 = *(const float4*)(Xp + k0 + 4);
      } else {
        rb0 = *(const float4*)(Wp + (size_t)k0 * M_DIM);
        rb1 = *(const float4*)(Wp + (size_t)(k0 + 1) * M_DIM);
      }
    }
    const s16x8 ah = *(const s16x8*)&sm.g.Ah[cur][m0 + fr][fq];
    const s16x8 al = *(const s16x8*)&sm.g.Al[cur][m0 + fr][fq];
    const s16x8 bh = *(const s16x8*)&sm.g.Bh[cur][n0 + fr][fq];
    const s16x8 bl = *(const s16x8*)&sm.g.Bl[cur][n0 + fr][fq];
    acc = __builtin_amdgcn_mfma_f32_16x16x32_bf16(ah, bh, acc, 0, 0, 0);
    acc = __builtin_amdgcn_mfma_f32_16x16x32_bf16(al, bh, acc, 0, 0, 0);
    acc = __builtin_amdgcn_mfma_f32_16x16x32_bf16(ah, bl, acc, 0, 0, 0);
    if (it + 1 < NSTEP) STAGE(cur ^ 1);
    __syncthreads();
  }

  const int rr0 = (lane >> 4) * 4;
#pragma unroll
  for (int r = 0; r < 4; ++r)
    feat[(size_t)(rt * 32 + m0 + rr0 + r) * M_DIM + bn + n0 + fr] =
        fmaxf(acc[r], 0.0f);
}

// ---------------------------------------------------------------------------
// phi/mu unit (R19 body): rows id[s] (fallback) or fb+s (sorted, id==null).
// ---------------------------------------------------------------------------
__device__ __forceinline__ void phimu_unit(
    int c, int sub, int n, int fb, const int* __restrict__ id, int t,
    const float* __restrict__ feat, float* __restrict__ phi,
    float* __restrict__ mu, float* __restrict__ cnt_out, SMem& sm) {
  if (sub == 16) {  // mu / count
    float2 acc = make_float2(0.f, 0.f);
    for (int s = 0; s < n; ++s) {
      const int row = id ? id[s] : fb + s;
      const float2 q = *(const float2*)&feat[(size_t)row * M_DIM + t * 2];
      acc.x += q.x;
      acc.y += q.y;
    }
    *(float2*)&mu[(size_t)c * M_DIM + t * 2] = acc;
    if (t == 0) cnt_out[c] = (float)n;
    return;
  }

  const int px = sub;
  const int tr = t >> 6;
  const int tc = t & 63;

  float acc[8][8] = {};

  for (int s0 = 0; s0 < n; s0 += 16) {
    const int chunk  = min(16, n - s0);
    if (s0) __syncthreads();
    const int nslots = chunk << 7;
    for (int v = t; v < nslots; v += 256) {
      const int sl = v >> 7;
      const int fp = (v & 127) << 2;
      const int row = id ? id[s0 + sl] : fb + s0 + sl;
      *(float4*)&sm.F[sl][fp] = *(const float4*)&feat[(size_t)row * M_DIM + fp];
    }
    __syncthreads();
    for (int sl = 0; sl < chunk; ++sl) {
      const float4 a0 = *(const float4*)&sm.F[sl][px * 32 + tr * 8];
      const float4 a1 = *(const float4*)&sm.F[sl][px * 32 + tr * 8 + 4];
      const float4 b0 = *(const float4*)&sm.F[sl][tc * 4];
      const float4 b1 = *(const float4*)&sm.F[sl][256 + tc * 4];
      const float av[8] = {a0.x, a0.y, a0.z, a0.w, a1.x, a1.y, a1.z, a1.w};
      const float bv[8] = {b0.x, b0.y, b0.z, b0.w, b1.x, b1.y, b1.z, b1.w};
#pragma unroll
      for (int r = 0; r < 8; ++r)
#pragma unroll
        for (int q = 0; q < 8; ++q)
          acc[r][q] += av[r] * bv[q];
    }
  }

  float* __restrict__ out = phi + (size_t)c * M_DIM * M_DIM;
#pragma unroll
  for (int r = 0; r < 8; ++r) {
    const size_t row = (size_t)(px * 32 + tr * 8 + r) * M_DIM;
    const f32x4 o0 = {acc[r][0], acc[r][1], acc[r][2], acc[r][3]};
    const f32x4 o1 = {acc[r][4], acc[r][5], acc[r][6], acc[r][7]};
    __builtin_nontemporal_store(o0, (f32x4*)&out[row + tc * 4]);
    __builtin_nontemporal_store(o1, (f32x4*)&out[row + 256 + tc * 4]);
  }
}

// ---------------------------------------------------------------------------
// Fused cooperative kernel: sorted-feat producer/consumer with per-tile flags.
// ---------------------------------------------------------------------------
__global__ __launch_bounds__(256) void fused_kernel(
    const float* __restrict__ X, const float* __restrict__ W,
    const int* __restrict__ labels, float* __restrict__ feat,
    int* __restrict__ counts_g, int* __restrict__ base_g,
    int* __restrict__ smap, int* __restrict__ tile_done,
    int* __restrict__ flag, float* __restrict__ phi,
    float* __restrict__ mu, float* __restrict__ cnt_out) {
  __shared__ SMem sm;
  const int t = threadIdx.x;
  const int b = (int)blockIdx.x;

  if (b == 0) {  // ---- index build: counts, prefix, sorted sample map ----
    for (int i = t; i < B_N; i += 256) sm.ix.lab[i] = labels[i];
    __syncthreads();
    const int w = t >> 6, lane = t & 63;
    for (int i = 0; i < 25; ++i) {
      const int c = w * 25 + i;
      int cnt = 0;
      for (int ch = 0; ch < 16; ++ch)
        cnt += __popcll(__ballot(sm.ix.lab[ch * 64 + lane] == c));
      if (lane == 0) sm.ix.cnt[c] = cnt;
    }
    __syncthreads();
    if (t == 0) {
      int acc = 0;
      for (int c = 0; c < C_N; ++c) { sm.ix.base[c] = acc; acc += sm.ix.cnt[c]; }
    }
    __syncthreads();
    for (int i = 0; i < 25; ++i) {
      const int c = w * 25 + i;
      int off = sm.ix.base[c];
      for (int ch = 0; ch < 16; ++ch) {
        const int j = ch * 64 + lane;
        const bool hit = (sm.ix.lab[j] == c);
        const unsigned long long mask = __ballot(hit);
        if (hit)
          smap[off + __popcll(mask & ((1ull << lane) - 1ull))] = j;
        off += __popcll(mask);
      }
    }
    if (t < C_N) {
      counts_g[t] = sm.ix.cnt[t];
      base_g[t]   = sm.ix.base[t];
    }
    __threadfence();
    __syncthreads();
    if (t == 0) atomicExch(flag, 1);
  } else {
    if (t == 0)
      while (atomicAdd(flag, 0) == 0) __builtin_amdgcn_s_sleep(4);
    __syncthreads();
  }
  __threadfence();  // acquire: smap/counts visible

  // ---- gemm: one unit per block (block 0 takes the last tile) ----
  const int g  = (b + GRID_N - 1) & (GRID_N - 1);
  const int rt = g >> 4, ct = g & 15;
  if (t < 32) sm.g.smp[t] = smap[rt * 32 + t];
  __syncthreads();
  gemm_unit(rt, ct, t, X, W, feat, sm);
  __threadfence();
  __syncthreads();
  if (t == 0) atomicAdd(&tile_done[rt], 1);

  // ---- phi/mu: grid-stride, spin per-class tiles ----
  for (int u = b; u < NUNITS; u += GRID_N) {
    const int c   = u / 17;
    const int sub = u - c * 17;
    const int n   = counts_g[c];
    const int fb  = base_g[c];
    if (n > 0 && t == 0) {
      const int lo = fb >> 5, hi = (fb + n - 1) >> 5;
      for (int r2 = lo; r2 <= hi; ++r2)
        while (atomicAdd(&tile_done[r2], 0) < 16) __builtin_amdgcn_s_sleep(4);
    }
    __syncthreads();
    __threadfence();
    phimu_unit(c, sub, n, fb, nullptr, t, feat, phi, mu, cnt_out, sm);
  }
}

// ---------------------------------------------------------------------------
// Fallback (R19 two-kernel path).
// ---------------------------------------------------------------------------
__global__ __launch_bounds__(256) void gemm_index_kernel(
    const float* __restrict__ X, const float* __restrict__ W,
    const int* __restrict__ labels, float* __restrict__ feat,
    int* __restrict__ counts, int* __restrict__ idx) {
  __shared__ SMem sm;
  const int t = threadIdx.x;
  const int b = (int)blockIdx.x;

  if (b >= NGEMM) {  // index path (R19)
    for (int i = t; i < B_N; i += 256) sm.ix.lab[i] = labels[i];
    __syncthreads();
    const int w = t >> 6, lane = t & 63;
    const int c = (b - NGEMM) * 4 + w;
    if (c < C_N) {
      int base = 0;
      for (int ch = 0; ch < 16; ++ch) {
        const int j = ch * 64 + lane;
        const bool hit = (sm.ix.lab[j] == c);
        const unsigned long long mask = __ballot(hit);
        if (hit)
          idx[c * B_N + base + __popcll(mask & ((1ull << lane) - 1ull))] = j;
        base += __popcll(mask);
      }
      if (lane == 0) counts[c] = base;
    }
    return;
  }
  const int rt = b >> 4, ct = b & 15;
  if (t < 32) sm.g.smp[t] = rt * 32 + t;  // identity row map
  __syncthreads();
  gemm_unit(rt, ct, t, X, W, feat, sm);
}

__global__ __launch_bounds__(256, 4) void phi_mu_kernel(
    const float* __restrict__ feat, const int* __restrict__ counts,
    const int* __restrict__ idx, float* __restrict__ phi,
    float* __restrict__ mu, float* __restrict__ cnt_out) {
  __shared__ SMem sm;
  const int c = blockIdx.y;
  phimu_unit(c, (int)blockIdx.x, counts[c], 0, idx + c * B_N,
             (int)threadIdx.x, feat, phi, mu, cnt_out, sm);
}

// ---------------------------------------------------------------------------
extern "C" void kernel_launch(void* const* d_in, const int* in_sizes, int n_in,
                              void* d_out, int out_size, void* d_ws,
                              size_t ws_size, hipStream_t stream) {
  const float* X      = (const float*)d_in[0];
  const float* W      = (const float*)d_in[1];
  const int*   labels = (const int*)d_in[2];

  float* out = (float*)d_out;
  float* phi = out;                                // C*M*M
  float* mu  = out + (size_t)C_N * M_DIM * M_DIM;  // C*M
  float* cnt = mu + (size_t)C_N * M_DIM;           // C

  char* w0 = (char*)d_ws;
  float* feat      = (float*)w0;                           // 2 MB
  int*   counts    = (int*)(w0 + (size_t)B_N * M_DIM * 4); // 128
  int*   idx       = counts + 128;                         // C*B (fallback)
  int*   smap      = idx + C_N * B_N;                      // 1024
  int*   base_g    = smap + 1024;                          // 128
  int*   tile_done = base_g + 128;                         // 32
  int*   flag      = tile_done + 32;                       // 1

  int maxPerCU = 0;
  hipError_t qerr = hipOccupancyMaxActiveBlocksPerMultiprocessor(
      &maxPerCU, fused_kernel, 256, 0);

  if (qerr == hipSuccess && maxPerCU * 256 >= GRID_N) {
    hipMemsetAsync(tile_done, 0, 33 * sizeof(int), stream);
    void* args[] = {(void*)&X,      (void*)&W,    (void*)&labels,
                    (void*)&feat,   (void*)&counts, (void*)&base_g,
                    (void*)&smap,   (void*)&tile_done, (void*)&flag,
                    (void*)&phi,    (void*)&mu,   (void*)&cnt};
    hipError_t lerr = hipLaunchCooperativeKernel(
        (const void*)fused_kernel, dim3(GRID_N), dim3(256), args, 0, stream);
    if (lerr == hipSuccess) return;
  }

  hipLaunchKernelGGL(gemm_index_kernel, dim3(NGEMM + NIDX), dim3(256), 0,
                     stream, X, W, labels, feat, counts, idx);
  hipLaunchKernelGGL(phi_mu_kernel, dim3(17, C_N), dim3(256), 0, stream,
                     feat, counts, idx, phi, mu, cnt);
}

// Round 22
// 41.671 us; speedup vs baseline: 9.5067x; 9.5067x over previous
//
#include <hip/hip_runtime.h>

#define B_N    1024
#define F_DIMC 768
#define M_DIM  512
#define C_N    100
#define KSTEP  32
#define NSTEP  (F_DIMC / KSTEP)   // 24 k-steps
#define NGEMM  512                // 32 row-tiles x 16 col-tiles (32x32 out)
#define NIDX   25                 // 25 blocks x 4 waves = 100 classes

typedef float f32x4 __attribute__((ext_vector_type(4)));
typedef short s16x8 __attribute__((ext_vector_type(8)));

// v_cvt_pk_bf16_f32: dst[15:0] = bf16(lo), dst[31:16] = bf16(hi). RNE.
__device__ __forceinline__ unsigned int cvt_pk_bf16(float lo, float hi) {
  unsigned int r;
  asm("v_cvt_pk_bf16_f32 %0, %1, %2" : "=v"(r) : "v"(lo), "v"(hi));
  return r;
}
__device__ __forceinline__ float bflo(unsigned int u) {
  return __builtin_bit_cast(float, u << 16);
}
__device__ __forceinline__ float bfhi(unsigned int u) {
  return __builtin_bit_cast(float, u & 0xffff0000u);
}

// ---------------------------------------------------------------------------
// Kernel 1 (R19 verbatim): MFMA gemm feat = relu(X@W) (split-bf16, 3-term,
// cvt_pk staging) + ballot-rank index build.
// ---------------------------------------------------------------------------
__global__ __launch_bounds__(256) void gemm_index_kernel(
    const float* __restrict__ X, const float* __restrict__ W,
    const int* __restrict__ labels, float* __restrict__ feat,
    int* __restrict__ counts, int* __restrict__ idx) {
  __shared__ unsigned short Ah[2][32][40], Al[2][32][40];  // [row][k] 80B pitch
  __shared__ unsigned short Bh[2][32][40], Bl[2][32][40];  // [col][k] 80B pitch
  __shared__ int lab[B_N];

  const int t = threadIdx.x;
  const int b = (int)blockIdx.x;

  if (b >= NGEMM) {  // ---- index path ----
    for (int i = t; i < B_N; i += 256) lab[i] = labels[i];
    __syncthreads();
    const int w    = t >> 6;
    const int lane = t & 63;
    const int c    = (b - NGEMM) * 4 + w;
    if (c < C_N) {
      int base = 0;
      for (int ch = 0; ch < 16; ++ch) {
        const int j = ch * 64 + lane;
        const bool hit = (lab[j] == c);
        const unsigned long long mask = __ballot(hit);
        if (hit) {
          const int r = __popcll(mask & ((1ull << lane) - 1ull));
          idx[c * B_N + base + r] = j;
        }
        base += __popcll(mask);
      }
      if (lane == 0) counts[c] = base;
    }
    return;
  }

  // ---- MFMA gemm path ----
  const int bm = (b >> 4) * 32;   // 32 row tiles
  const int bn = (b & 15) * 32;   // 16 col tiles

  const bool isX = (t < 128);
  const int xr = t >> 2;              // 0..31 row
  const int xk = (t & 3) * 8;         // 0,8,16,24 k-offset
  const int uu = isX ? 0 : (t - 128);
  const int wk = (uu >> 3) * 2;       // 0..30 even k
  const int wc = (uu & 7) * 4;        // 0..28 col base

  const float* __restrict__ Xp = X + (size_t)(bm + xr) * F_DIMC + xk;
  const float* __restrict__ Wp = W + (size_t)wk * M_DIM + bn + wc;

  const int lane = t & 63;
  const int wv   = t >> 6;
  const int m0 = (wv & 1) * 16;
  const int n0 = (wv >> 1) * 16;
  const int fr = lane & 15;
  const int fq = (lane >> 4) * 8;

  f32x4 acc = {0.f, 0.f, 0.f, 0.f};

  float4 ra0, ra1, rb0, rb1;
  if (isX) {
    ra0 = *(const float4*)(Xp);
    ra1 = *(const float4*)(Xp + 4);
  } else {
    rb0 = *(const float4*)(Wp);
    rb1 = *(const float4*)(Wp + M_DIM);
  }

  auto STAGE = [&](int buf) {
    if (isX) {
      const float v[8] = {ra0.x, ra0.y, ra0.z, ra0.w,
                          ra1.x, ra1.y, ra1.z, ra1.w};
      unsigned int hu[4], lu[4];
#pragma unroll
      for (int j = 0; j < 4; ++j) {
        hu[j] = cvt_pk_bf16(v[2 * j], v[2 * j + 1]);
        const float l0 = v[2 * j] - bflo(hu[j]);
        const float l1 = v[2 * j + 1] - bfhi(hu[j]);
        lu[j] = cvt_pk_bf16(l0, l1);
      }
      *(uint4*)&Ah[buf][xr][xk] = make_uint4(hu[0], hu[1], hu[2], hu[3]);
      *(uint4*)&Al[buf][xr][xk] = make_uint4(lu[0], lu[1], lu[2], lu[3]);
    } else {
      const float a[4] = {rb0.x, rb0.y, rb0.z, rb0.w};
      const float d[4] = {rb1.x, rb1.y, rb1.z, rb1.w};
#pragma unroll
      for (int i = 0; i < 4; ++i) {
        const unsigned int h = cvt_pk_bf16(a[i], d[i]);
        const float la = a[i] - bflo(h);
        const float ld = d[i] - bfhi(h);
        const unsigned int l = cvt_pk_bf16(la, ld);
        *(unsigned int*)&Bh[buf][wc + i][wk] = h;
        *(unsigned int*)&Bl[buf][wc + i][wk] = l;
      }
    }
  };

  STAGE(0);
  __syncthreads();

  for (int it = 0; it < NSTEP; ++it) {
    const int cur = it & 1;
    if (it + 1 < NSTEP) {
      const int k0 = (it + 1) * KSTEP;
      if (isX) {
        ra0 = *(const float4*)(Xp + k0);
        ra1 = *(const float4*)(Xp + k0 + 4);
      } else {
        rb0 = *(const float4*)(Wp + (size_t)k0 * M_DIM);
        rb1 = *(const float4*)(Wp + (size_t)(k0 + 1) * M_DIM);
      }
    }
    const s16x8 ah = *(const s16x8*)&Ah[cur][m0 + fr][fq];
    const s16x8 al = *(const s16x8*)&Al[cur][m0 + fr][fq];
    const s16x8 bh = *(const s16x8*)&Bh[cur][n0 + fr][fq];
    const s16x8 bl = *(const s16x8*)&Bl[cur][n0 + fr][fq];
    acc = __builtin_amdgcn_mfma_f32_16x16x32_bf16(ah, bh, acc, 0, 0, 0);
    acc = __builtin_amdgcn_mfma_f32_16x16x32_bf16(al, bh, acc, 0, 0, 0);
    acc = __builtin_amdgcn_mfma_f32_16x16x32_bf16(ah, bl, acc, 0, 0, 0);
    if (it + 1 < NSTEP) STAGE(cur ^ 1);
    __syncthreads();
  }

  // store with relu; C layout (verified): col = lane&15, row = (lane>>4)*4+r
  const int r0 = (lane >> 4) * 4;
#pragma unroll
  for (int r = 0; r < 4; ++r)
    feat[(size_t)(bm + m0 + r0 + r) * M_DIM + bn + n0 + fr] =
        fmaxf(acc[r], 0.0f);
}

// ---------------------------------------------------------------------------
// Kernel 2: phi 32-row panels + mu/count. Stage buffer in bf16 (16 KB) —
// halves LDS footprint (static residency 5->10 blocks/CU) and LDS read
// bytes; fp32 FMA on unpacked values; fp32 nt stores. mu stays fp32-exact.
// grid = (17, C): panels 0..15 -> 32 rows x 512 cols; panel 16 -> mu/count.
// ---------------------------------------------------------------------------
__global__ __launch_bounds__(256, 4) void phi_mu_kernel(
    const float* __restrict__ feat, const int* __restrict__ counts,
    const int* __restrict__ idx, float* __restrict__ phi,
    float* __restrict__ mu, float* __restrict__ cnt_out) {
  const int c = blockIdx.y;
  const int n = counts[c];
  const int* __restrict__ id = idx + c * B_N;
  const int t = threadIdx.x;

  if (blockIdx.x == 16) {  // ---- mu / count path (fp32 exact) ----
    float2 acc = make_float2(0.f, 0.f);
    for (int s = 0; s < n; ++s) {
      const float2 q = *(const float2*)&feat[(size_t)id[s] * M_DIM + t * 2];
      acc.x += q.x;
      acc.y += q.y;
    }
    *(float2*)&mu[(size_t)c * M_DIM + t * 2] = acc;
    if (t == 0) cnt_out[c] = (float)n;
    return;
  }

  // ---- phi row-panel path: rows 32*px..+32, all 512 cols ----
  const int px = (int)blockIdx.x;      // 0..15
  const int tr = t >> 6;               // row group 0..3 (x8 rows)
  const int tc = t & 63;               // cols tc*4 and 256+tc*4

  __shared__ unsigned short F[16][M_DIM];  // bf16, 16 KB

  float acc[8][8] = {};

  for (int s0 = 0; s0 < n; s0 += 16) {
    const int chunk  = min(16, n - s0);
    if (s0) __syncthreads();           // protect F before overwrite
    const int nslots = chunk << 7;     // chunk * 128 float4-source slots
    for (int v = t; v < nslots; v += 256) {
      const int sl = v >> 7;
      const int fp = (v & 127) << 2;   // ushort index, 8B-aligned
      const float4 q =
          *(const float4*)&feat[(size_t)id[s0 + sl] * M_DIM + fp];
      const unsigned int p0 = cvt_pk_bf16(q.x, q.y);
      const unsigned int p1 = cvt_pk_bf16(q.z, q.w);
      *(uint2*)&F[sl][fp] = make_uint2(p0, p1);
    }
    __syncthreads();
    for (int sl = 0; sl < chunk; ++sl) {
      const uint4 au  = *(const uint4*)&F[sl][px * 32 + tr * 8];  // bcast 16B
      const uint2 b0u = *(const uint2*)&F[sl][tc * 4];            // contig 8B
      const uint2 b1u = *(const uint2*)&F[sl][256 + tc * 4];      // contig 8B
      const float av[8] = {bflo(au.x), bfhi(au.x), bflo(au.y), bfhi(au.y),
                           bflo(au.z), bfhi(au.z), bflo(au.w), bfhi(au.w)};
      const float bv[8] = {bflo(b0u.x), bfhi(b0u.x), bflo(b0u.y), bfhi(b0u.y),
                           bflo(b1u.x), bfhi(b1u.x), bflo(b1u.y), bfhi(b1u.y)};
#pragma unroll
      for (int r = 0; r < 8; ++r)
#pragma unroll
        for (int q = 0; q < 8; ++q)
          acc[r][q] += av[r] * bv[q];
    }
  }

  float* __restrict__ out = phi + (size_t)c * M_DIM * M_DIM;
#pragma unroll
  for (int r = 0; r < 8; ++r) {
    const size_t row = (size_t)(px * 32 + tr * 8 + r) * M_DIM;
    const f32x4 o0 = {acc[r][0], acc[r][1], acc[r][2], acc[r][3]};
    const f32x4 o1 = {acc[r][4], acc[r][5], acc[r][6], acc[r][7]};
    __builtin_nontemporal_store(o0, (f32x4*)&out[row + tc * 4]);
    __builtin_nontemporal_store(o1, (f32x4*)&out[row + 256 + tc * 4]);
  }
}

// ---------------------------------------------------------------------------
extern "C" void kernel_launch(void* const* d_in, const int* in_sizes, int n_in,
                              void* d_out, int out_size, void* d_ws,
                              size_t ws_size, hipStream_t stream) {
  const float* X      = (const float*)d_in[0];
  const float* W      = (const float*)d_in[1];
  const int*   labels = (const int*)d_in[2];

  float* out = (float*)d_out;
  float* phi = out;                                // C*M*M
  float* mu  = out + (size_t)C_N * M_DIM * M_DIM;  // C*M
  float* cnt = mu + (size_t)C_N * M_DIM;           // C

  float* feat   = (float*)d_ws;                    // B*M fp32 = 2 MB
  int*   counts = (int*)((char*)d_ws + (size_t)B_N * M_DIM * sizeof(float));
  int*   idx    = counts + 128;                    // C*B ints

  hipLaunchKernelGGL(gemm_index_kernel, dim3(NGEMM + NIDX), dim3(256), 0,
                     stream, X, W, labels, feat, counts, idx);
  hipLaunchKernelGGL(phi_mu_kernel, dim3(17, C_N), dim3(256), 0, stream,
                     feat, counts, idx, phi, mu, cnt);
}

// Round 23
// 39.340 us; speedup vs baseline: 10.0699x; 1.0592x over previous
//
#include <hip/hip_runtime.h>

#define B_N    1024
#define F_DIMC 768
#define M_DIM  512
#define C_N    100
#define KHALF  (F_DIMC / 2)       // 384 per K-split half
#define KSTEP  32
#define NSTEP2 (KHALF / KSTEP)    // 12 k-steps per half
#define NGEMM  256                // 128 tiles (16x8 of 64x64) x 2 K-halves
#define NIDX   13                 // 13 blocks x 8 waves = 104 >= 100 classes

typedef float f32x4 __attribute__((ext_vector_type(4)));
typedef short s16x8 __attribute__((ext_vector_type(8)));

// v_cvt_pk_bf16_f32: dst[15:0] = bf16(lo), dst[31:16] = bf16(hi). RNE.
__device__ __forceinline__ unsigned int cvt_pk_bf16(float lo, float hi) {
  unsigned int r;
  asm("v_cvt_pk_bf16_f32 %0, %1, %2" : "=v"(r) : "v"(lo), "v"(hi));
  return r;
}
__device__ __forceinline__ float bflo(unsigned int u) {
  return __builtin_bit_cast(float, u << 16);
}
__device__ __forceinline__ float bfhi(unsigned int u) {
  return __builtin_bit_cast(float, u & 0xffff0000u);
}

// ---------------------------------------------------------------------------
// Kernel 1: MFMA partial gemm (split-bf16 3-term, 64x64 tile, K-split x2,
// 512 thr / 8 waves) + ballot-rank index build.
// Staged bytes per FLOP halved vs the 32x32 version: each k-step stages
// A(64x32)+B(32x64) hi/lo for a 64x64 output tile.
// ---------------------------------------------------------------------------
__global__ __launch_bounds__(512) void gemm_index_kernel(
    const float* __restrict__ X, const float* __restrict__ W,
    const int* __restrict__ labels, float* __restrict__ part,
    int* __restrict__ counts, int* __restrict__ idx) {
  __shared__ unsigned short Ah[2][64][40], Al[2][64][40];  // [row][k] 80B pitch
  __shared__ unsigned short Bh[2][64][40], Bl[2][64][40];  // [col][k] 80B pitch
  __shared__ int lab[B_N];

  const int t = threadIdx.x;
  const int b = (int)blockIdx.x;

  if (b >= NGEMM) {  // ---- index path: one wave per class ----
    for (int i = t; i < B_N; i += 512) lab[i] = labels[i];
    __syncthreads();
    const int w    = t >> 6;
    const int lane = t & 63;
    const int c    = (b - NGEMM) * 8 + w;
    if (c < C_N) {
      int base = 0;
      for (int ch = 0; ch < 16; ++ch) {
        const int j = ch * 64 + lane;
        const bool hit = (lab[j] == c);
        const unsigned long long mask = __ballot(hit);
        if (hit) {
          const int r = __popcll(mask & ((1ull << lane) - 1ull));
          idx[c * B_N + base + r] = j;
        }
        base += __popcll(mask);
      }
      if (lane == 0) counts[c] = base;
    }
    return;
  }

  // ---- MFMA gemm path ----
  const int kb   = b >> 7;          // K-half 0/1
  const int tile = b & 127;         // 0..127
  const int bm = (tile >> 3) * 64;  // 16 row tiles
  const int bn = (tile & 7) * 64;   // 8 col tiles

  // staging roles: threads 0..255 stage X (64r x 32k, 8 f32 each);
  //                threads 256..511 stage W (32k x 64c, 8 f32 each).
  const bool isX = (t < 256);
  const int xr = t >> 2;              // 0..63 row
  const int xk = (t & 3) * 8;         // 0,8,16,24 k-offset
  const int uu = isX ? 0 : (t - 256); // 0..255
  const int wk = (uu >> 4) * 2;       // 0..30 even k
  const int wc = (uu & 15) * 4;       // 0..60 col base

  const float* __restrict__ Xp =
      X + (size_t)(bm + xr) * F_DIMC + kb * KHALF + xk;
  const float* __restrict__ Wp =
      W + (size_t)(kb * KHALF + wk) * M_DIM + bn + wc;

  // compute roles: wave wv owns subtiles (mt, nh*2) and (mt, nh*2+1)
  const int lane = t & 63;
  const int wv   = t >> 6;          // 0..7
  const int m0 = (wv & 3) * 16;     // 4 m-tiles
  const int nh = wv >> 2;           // 0/1 -> n-tiles nh*2, nh*2+1
  const int fr = lane & 15;
  const int fq = (lane >> 4) * 8;

  f32x4 acc0 = {0.f, 0.f, 0.f, 0.f};
  f32x4 acc1 = {0.f, 0.f, 0.f, 0.f};

  float4 ra0, ra1, rb0, rb1;
  if (isX) {
    ra0 = *(const float4*)(Xp);
    ra1 = *(const float4*)(Xp + 4);
  } else {
    rb0 = *(const float4*)(Wp);
    rb1 = *(const float4*)(Wp + M_DIM);
  }

  auto STAGE = [&](int buf) {
    if (isX) {
      const float v[8] = {ra0.x, ra0.y, ra0.z, ra0.w,
                          ra1.x, ra1.y, ra1.z, ra1.w};
      unsigned int hu[4], lu[4];
#pragma unroll
      for (int j = 0; j < 4; ++j) {
        hu[j] = cvt_pk_bf16(v[2 * j], v[2 * j + 1]);
        const float l0 = v[2 * j] - bflo(hu[j]);
        const float l1 = v[2 * j + 1] - bfhi(hu[j]);
        lu[j] = cvt_pk_bf16(l0, l1);
      }
      *(uint4*)&Ah[buf][xr][xk] = make_uint4(hu[0], hu[1], hu[2], hu[3]);
      *(uint4*)&Al[buf][xr][xk] = make_uint4(lu[0], lu[1], lu[2], lu[3]);
    } else {
      const float a[4] = {rb0.x, rb0.y, rb0.z, rb0.w};   // k = wk
      const float d[4] = {rb1.x, rb1.y, rb1.z, rb1.w};   // k = wk+1
#pragma unroll
      for (int i = 0; i < 4; ++i) {
        const unsigned int h = cvt_pk_bf16(a[i], d[i]);
        const float la = a[i] - bflo(h);
        const float ld = d[i] - bfhi(h);
        const unsigned int l = cvt_pk_bf16(la, ld);
        *(unsigned int*)&Bh[buf][wc + i][wk] = h;
        *(unsigned int*)&Bl[buf][wc + i][wk] = l;
      }
    }
  };

  STAGE(0);
  __syncthreads();

  for (int it = 0; it < NSTEP2; ++it) {
    const int cur = it & 1;
    if (it + 1 < NSTEP2) {
      const int k0 = (it + 1) * KSTEP;
      if (isX) {
        ra0 = *(const float4*)(Xp + k0);
        ra1 = *(const float4*)(Xp + k0 + 4);
      } else {
        rb0 = *(const float4*)(Wp + (size_t)k0 * M_DIM);
        rb1 = *(const float4*)(Wp + (size_t)(k0 + 1) * M_DIM);
      }
    }
    const s16x8 ah = *(const s16x8*)&Ah[cur][m0 + fr][fq];
    const s16x8 al = *(const s16x8*)&Al[cur][m0 + fr][fq];
    {
      const s16x8 bh = *(const s16x8*)&Bh[cur][(nh * 2) * 16 + fr][fq];
      const s16x8 bl = *(const s16x8*)&Bl[cur][(nh * 2) * 16 + fr][fq];
      acc0 = __builtin_amdgcn_mfma_f32_16x16x32_bf16(ah, bh, acc0, 0, 0, 0);
      acc0 = __builtin_amdgcn_mfma_f32_16x16x32_bf16(al, bh, acc0, 0, 0, 0);
      acc0 = __builtin_amdgcn_mfma_f32_16x16x32_bf16(ah, bl, acc0, 0, 0, 0);
    }
    {
      const s16x8 bh = *(const s16x8*)&Bh[cur][(nh * 2 + 1) * 16 + fr][fq];
      const s16x8 bl = *(const s16x8*)&Bl[cur][(nh * 2 + 1) * 16 + fr][fq];
      acc1 = __builtin_amdgcn_mfma_f32_16x16x32_bf16(ah, bh, acc1, 0, 0, 0);
      acc1 = __builtin_amdgcn_mfma_f32_16x16x32_bf16(al, bh, acc1, 0, 0, 0);
      acc1 = __builtin_amdgcn_mfma_f32_16x16x32_bf16(ah, bl, acc1, 0, 0, 0);
    }
    if (it + 1 < NSTEP2) STAGE(cur ^ 1);
    __syncthreads();
  }

  // store partials (no relu); C layout: col = lane&15, row = (lane>>4)*4+r
  float* __restrict__ dst = part + (size_t)kb * B_N * M_DIM;
  const int rr0 = (lane >> 4) * 4;
#pragma unroll
  for (int r = 0; r < 4; ++r) {
    const size_t row = (size_t)(bm + m0 + rr0 + r) * M_DIM;
    dst[row + bn + (nh * 2) * 16 + fr]     = acc0[r];
    dst[row + bn + (nh * 2 + 1) * 16 + fr] = acc1[r];
  }
}

// ---------------------------------------------------------------------------
// Kernel 2 (R8 verbatim): phi 32-row panels + mu/count, feat = relu(p0+p1)
// built in staging. grid = (17, C); panel 16 -> mu/count.
// ---------------------------------------------------------------------------
__global__ __launch_bounds__(256, 4) void phi_mu_kernel(
    const float* __restrict__ p0, const float* __restrict__ p1,
    const int* __restrict__ counts, const int* __restrict__ idx,
    float* __restrict__ phi, float* __restrict__ mu,
    float* __restrict__ cnt_out) {
  const int c = blockIdx.y;
  const int n = counts[c];
  const int* __restrict__ id = idx + c * B_N;
  const int t = threadIdx.x;

  if (blockIdx.x == 16) {  // ---- mu / count path ----
    float2 acc = make_float2(0.f, 0.f);
    for (int s = 0; s < n; ++s) {
      const size_t o = (size_t)id[s] * M_DIM + t * 2;
      const float2 q0 = *(const float2*)&p0[o];
      const float2 q1 = *(const float2*)&p1[o];
      acc.x += fmaxf(q0.x + q1.x, 0.f);
      acc.y += fmaxf(q0.y + q1.y, 0.f);
    }
    *(float2*)&mu[(size_t)c * M_DIM + t * 2] = acc;
    if (t == 0) cnt_out[c] = (float)n;
    return;
  }

  // ---- phi row-panel path: rows 32*px..+32, all 512 cols ----
  const int px = (int)blockIdx.x;      // 0..15
  const int tr = t >> 6;               // row group 0..3 (x8 rows)
  const int tc = t & 63;               // cols tc*4 and 256+tc*4

  __shared__ float F[16][M_DIM];

  float acc[8][8] = {};

  for (int s0 = 0; s0 < n; s0 += 16) {
    const int chunk  = min(16, n - s0);
    if (s0) __syncthreads();           // protect F before overwrite
    const int nslots = chunk << 7;     // chunk * 128 float4 per row
    for (int v = t; v < nslots; v += 256) {
      const int sl   = v >> 7;
      const int fp   = (v & 127) << 2;
      const size_t o = (size_t)id[s0 + sl] * M_DIM + fp;
      const float4 q0 = *(const float4*)&p0[o];
      const float4 q1 = *(const float4*)&p1[o];
      float4 f;
      f.x = fmaxf(q0.x + q1.x, 0.f);
      f.y = fmaxf(q0.y + q1.y, 0.f);
      f.z = fmaxf(q0.z + q1.z, 0.f);
      f.w = fmaxf(q0.w + q1.w, 0.f);
      *(float4*)&F[sl][fp] = f;
    }
    __syncthreads();
    for (int sl = 0; sl < chunk; ++sl) {
      const float4 a0 = *(const float4*)&F[sl][px * 32 + tr * 8];      // bcast
      const float4 a1 = *(const float4*)&F[sl][px * 32 + tr * 8 + 4];  // bcast
      const float4 b0 = *(const float4*)&F[sl][tc * 4];        // contiguous
      const float4 b1 = *(const float4*)&F[sl][256 + tc * 4];  // contiguous
      const float av[8] = {a0.x, a0.y, a0.z, a0.w, a1.x, a1.y, a1.z, a1.w};
      const float bv[8] = {b0.x, b0.y, b0.z, b0.w, b1.x, b1.y, b1.z, b1.w};
#pragma unroll
      for (int r = 0; r < 8; ++r)
#pragma unroll
        for (int q = 0; q < 8; ++q)
          acc[r][q] += av[r] * bv[q];
    }
  }

  float* __restrict__ out = phi + (size_t)c * M_DIM * M_DIM;
#pragma unroll
  for (int r = 0; r < 8; ++r) {
    const size_t row = (size_t)(px * 32 + tr * 8 + r) * M_DIM;
    const f32x4 o0 = {acc[r][0], acc[r][1], acc[r][2], acc[r][3]};
    const f32x4 o1 = {acc[r][4], acc[r][5], acc[r][6], acc[r][7]};
    __builtin_nontemporal_store(o0, (f32x4*)&out[row + tc * 4]);
    __builtin_nontemporal_store(o1, (f32x4*)&out[row + 256 + tc * 4]);
  }
}

// ---------------------------------------------------------------------------
extern "C" void kernel_launch(void* const* d_in, const int* in_sizes, int n_in,
                              void* d_out, int out_size, void* d_ws,
                              size_t ws_size, hipStream_t stream) {
  const float* X      = (const float*)d_in[0];
  const float* W      = (const float*)d_in[1];
  const int*   labels = (const int*)d_in[2];

  float* out = (float*)d_out;
  float* phi = out;                                // C*M*M
  float* mu  = out + (size_t)C_N * M_DIM * M_DIM;  // C*M
  float* cnt = mu + (size_t)C_N * M_DIM;           // C

  float* part   = (float*)d_ws;                    // 2 x B*M fp32 = 4 MB
  int*   counts = (int*)((char*)d_ws + (size_t)2 * B_N * M_DIM * sizeof(float));
  int*   idx    = counts + 128;                    // C*B ints

  hipLaunchKernelGGL(gemm_index_kernel, dim3(NGEMM + NIDX), dim3(512), 0,
                     stream, X, W, labels, part, counts, idx);
  hipLaunchKernelGGL(phi_mu_kernel, dim3(17, C_N), dim3(256), 0, stream,
                     part, part + (size_t)B_N * M_DIM, counts, idx,
                     phi, mu, cnt);
}

// Round 24
// 38.605 us; speedup vs baseline: 10.2617x; 1.0191x over previous
//
#include <hip/hip_runtime.h>

#define B_N    1024
#define F_DIMC 768
#define M_DIM  512
#define C_N    100
#define KHALF  (F_DIMC / 2)       // 384 per K-split half
#define KSTEP  32
#define NSTEP2 (KHALF / KSTEP)    // 12 k-steps per half
#define NGEMM  256                // 128 tiles (16x8 of 64x64) x 2 K-halves
#define NIDX   13                 // 13 blocks x 8 waves = 104 >= 100 classes

typedef float f32x4 __attribute__((ext_vector_type(4)));
typedef short s16x8 __attribute__((ext_vector_type(8)));

// v_cvt_pk_bf16_f32: dst[15:0] = bf16(lo), dst[31:16] = bf16(hi). RNE.
__device__ __forceinline__ unsigned int cvt_pk_bf16(float lo, float hi) {
  unsigned int r;
  asm("v_cvt_pk_bf16_f32 %0, %1, %2" : "=v"(r) : "v"(lo), "v"(hi));
  return r;
}
__device__ __forceinline__ float bflo(unsigned int u) {
  return __builtin_bit_cast(float, u << 16);
}
__device__ __forceinline__ float bfhi(unsigned int u) {
  return __builtin_bit_cast(float, u & 0xffff0000u);
}

// ---------------------------------------------------------------------------
// Kernel 1: MFMA partial gemm (split-bf16 2-term: hh + lh; W single bf16,
// X hi/lo), 64x64 tile, K-split x2, 512 thr / 8 waves + index build.
// vs R23: Bl buffer + hl MFMA dropped (-33% MFMA, -25% LDS reads, W staging
// conversions halved). Residual error: X_hi*W_lo ~ 2^-9 rel -> phi ~0.05.
// ---------------------------------------------------------------------------
__global__ __launch_bounds__(512) void gemm_index_kernel(
    const float* __restrict__ X, const float* __restrict__ W,
    const int* __restrict__ labels, float* __restrict__ part,
    int* __restrict__ counts, int* __restrict__ idx) {
  __shared__ unsigned short Ah[2][64][40], Al[2][64][40];  // [row][k] 80B pitch
  __shared__ unsigned short Bh[2][64][40];                 // [col][k] 80B pitch
  __shared__ int lab[B_N];

  const int t = threadIdx.x;
  const int b = (int)blockIdx.x;

  if (b >= NGEMM) {  // ---- index path: one wave per class ----
    for (int i = t; i < B_N; i += 512) lab[i] = labels[i];
    __syncthreads();
    const int w    = t >> 6;
    const int lane = t & 63;
    const int c    = (b - NGEMM) * 8 + w;
    if (c < C_N) {
      int base = 0;
      for (int ch = 0; ch < 16; ++ch) {
        const int j = ch * 64 + lane;
        const bool hit = (lab[j] == c);
        const unsigned long long mask = __ballot(hit);
        if (hit) {
          const int r = __popcll(mask & ((1ull << lane) - 1ull));
          idx[c * B_N + base + r] = j;
        }
        base += __popcll(mask);
      }
      if (lane == 0) counts[c] = base;
    }
    return;
  }

  // ---- MFMA gemm path ----
  const int kb   = b >> 7;          // K-half 0/1
  const int tile = b & 127;         // 0..127
  const int bm = (tile >> 3) * 64;  // 16 row tiles
  const int bn = (tile & 7) * 64;   // 8 col tiles

  // staging roles: threads 0..255 stage X (64r x 32k, 8 f32 each);
  //                threads 256..511 stage W (32k x 64c, 8 f32 each).
  const bool isX = (t < 256);
  const int xr = t >> 2;              // 0..63 row
  const int xk = (t & 3) * 8;         // 0,8,16,24 k-offset
  const int uu = isX ? 0 : (t - 256); // 0..255
  const int wk = (uu >> 4) * 2;       // 0..30 even k
  const int wc = (uu & 15) * 4;       // 0..60 col base

  const float* __restrict__ Xp =
      X + (size_t)(bm + xr) * F_DIMC + kb * KHALF + xk;
  const float* __restrict__ Wp =
      W + (size_t)(kb * KHALF + wk) * M_DIM + bn + wc;

  // compute roles: wave wv owns subtiles (mt, nh*2) and (mt, nh*2+1)
  const int lane = t & 63;
  const int wv   = t >> 6;          // 0..7
  const int m0 = (wv & 3) * 16;     // 4 m-tiles
  const int nh = wv >> 2;           // 0/1 -> n-tiles nh*2, nh*2+1
  const int fr = lane & 15;
  const int fq = (lane >> 4) * 8;

  f32x4 acc0 = {0.f, 0.f, 0.f, 0.f};
  f32x4 acc1 = {0.f, 0.f, 0.f, 0.f};

  float4 ra0, ra1, rb0, rb1;
  if (isX) {
    ra0 = *(const float4*)(Xp);
    ra1 = *(const float4*)(Xp + 4);
  } else {
    rb0 = *(const float4*)(Wp);
    rb1 = *(const float4*)(Wp + M_DIM);
  }

  auto STAGE = [&](int buf) {
    if (isX) {
      const float v[8] = {ra0.x, ra0.y, ra0.z, ra0.w,
                          ra1.x, ra1.y, ra1.z, ra1.w};
      unsigned int hu[4], lu[4];
#pragma unroll
      for (int j = 0; j < 4; ++j) {
        hu[j] = cvt_pk_bf16(v[2 * j], v[2 * j + 1]);
        const float l0 = v[2 * j] - bflo(hu[j]);
        const float l1 = v[2 * j + 1] - bfhi(hu[j]);
        lu[j] = cvt_pk_bf16(l0, l1);
      }
      *(uint4*)&Ah[buf][xr][xk] = make_uint4(hu[0], hu[1], hu[2], hu[3]);
      *(uint4*)&Al[buf][xr][xk] = make_uint4(lu[0], lu[1], lu[2], lu[3]);
    } else {
      const float a[4] = {rb0.x, rb0.y, rb0.z, rb0.w};   // k = wk
      const float d[4] = {rb1.x, rb1.y, rb1.z, rb1.w};   // k = wk+1
#pragma unroll
      for (int i = 0; i < 4; ++i)
        *(unsigned int*)&Bh[buf][wc + i][wk] = cvt_pk_bf16(a[i], d[i]);
    }
  };

  STAGE(0);
  __syncthreads();

  for (int it = 0; it < NSTEP2; ++it) {
    const int cur = it & 1;
    if (it + 1 < NSTEP2) {
      const int k0 = (it + 1) * KSTEP;
      if (isX) {
        ra0 = *(const float4*)(Xp + k0);
        ra1 = *(const float4*)(Xp + k0 + 4);
      } else {
        rb0 = *(const float4*)(Wp + (size_t)k0 * M_DIM);
        rb1 = *(const float4*)(Wp + (size_t)(k0 + 1) * M_DIM);
      }
    }
    const s16x8 ah = *(const s16x8*)&Ah[cur][m0 + fr][fq];
    const s16x8 al = *(const s16x8*)&Al[cur][m0 + fr][fq];
    {
      const s16x8 bh = *(const s16x8*)&Bh[cur][(nh * 2) * 16 + fr][fq];
      acc0 = __builtin_amdgcn_mfma_f32_16x16x32_bf16(ah, bh, acc0, 0, 0, 0);
      acc0 = __builtin_amdgcn_mfma_f32_16x16x32_bf16(al, bh, acc0, 0, 0, 0);
    }
    {
      const s16x8 bh = *(const s16x8*)&Bh[cur][(nh * 2 + 1) * 16 + fr][fq];
      acc1 = __builtin_amdgcn_mfma_f32_16x16x32_bf16(ah, bh, acc1, 0, 0, 0);
      acc1 = __builtin_amdgcn_mfma_f32_16x16x32_bf16(al, bh, acc1, 0, 0, 0);
    }
    if (it + 1 < NSTEP2) STAGE(cur ^ 1);
    __syncthreads();
  }

  // store partials (no relu); C layout: col = lane&15, row = (lane>>4)*4+r
  float* __restrict__ dst = part + (size_t)kb * B_N * M_DIM;
  const int rr0 = (lane >> 4) * 4;
#pragma unroll
  for (int r = 0; r < 4; ++r) {
    const size_t row = (size_t)(bm + m0 + rr0 + r) * M_DIM;
    dst[row + bn + (nh * 2) * 16 + fr]     = acc0[r];
    dst[row + bn + (nh * 2 + 1) * 16 + fr] = acc1[r];
  }
}

// ---------------------------------------------------------------------------
// Kernel 2 (R8/R23 verbatim): phi 32-row panels + mu/count,
// feat = relu(p0+p1) built in staging. grid = (17, C); panel 16 -> mu/count.
// ---------------------------------------------------------------------------
__global__ __launch_bounds__(256, 4) void phi_mu_kernel(
    const float* __restrict__ p0, const float* __restrict__ p1,
    const int* __restrict__ counts, const int* __restrict__ idx,
    float* __restrict__ phi, float* __restrict__ mu,
    float* __restrict__ cnt_out) {
  const int c = blockIdx.y;
  const int n = counts[c];
  const int* __restrict__ id = idx + c * B_N;
  const int t = threadIdx.x;

  if (blockIdx.x == 16) {  // ---- mu / count path ----
    float2 acc = make_float2(0.f, 0.f);
    for (int s = 0; s < n; ++s) {
      const size_t o = (size_t)id[s] * M_DIM + t * 2;
      const float2 q0 = *(const float2*)&p0[o];
      const float2 q1 = *(const float2*)&p1[o];
      acc.x += fmaxf(q0.x + q1.x, 0.f);
      acc.y += fmaxf(q0.y + q1.y, 0.f);
    }
    *(float2*)&mu[(size_t)c * M_DIM + t * 2] = acc;
    if (t == 0) cnt_out[c] = (float)n;
    return;
  }

  // ---- phi row-panel path: rows 32*px..+32, all 512 cols ----
  const int px = (int)blockIdx.x;      // 0..15
  const int tr = t >> 6;               // row group 0..3 (x8 rows)
  const int tc = t & 63;               // cols tc*4 and 256+tc*4

  __shared__ float F[16][M_DIM];

  float acc[8][8] = {};

  for (int s0 = 0; s0 < n; s0 += 16) {
    const int chunk  = min(16, n - s0);
    if (s0) __syncthreads();           // protect F before overwrite
    const int nslots = chunk << 7;     // chunk * 128 float4 per row
    for (int v = t; v < nslots; v += 256) {
      const int sl   = v >> 7;
      const int fp   = (v & 127) << 2;
      const size_t o = (size_t)id[s0 + sl] * M_DIM + fp;
      const float4 q0 = *(const float4*)&p0[o];
      const float4 q1 = *(const float4*)&p1[o];
      float4 f;
      f.x = fmaxf(q0.x + q1.x, 0.f);
      f.y = fmaxf(q0.y + q1.y, 0.f);
      f.z = fmaxf(q0.z + q1.z, 0.f);
      f.w = fmaxf(q0.w + q1.w, 0.f);
      *(float4*)&F[sl][fp] = f;
    }
    __syncthreads();
    for (int sl = 0; sl < chunk; ++sl) {
      const float4 a0 = *(const float4*)&F[sl][px * 32 + tr * 8];      // bcast
      const float4 a1 = *(const float4*)&F[sl][px * 32 + tr * 8 + 4];  // bcast
      const float4 b0 = *(const float4*)&F[sl][tc * 4];        // contiguous
      const float4 b1 = *(const float4*)&F[sl][256 + tc * 4];  // contiguous
      const float av[8] = {a0.x, a0.y, a0.z, a0.w, a1.x, a1.y, a1.z, a1.w};
      const float bv[8] = {b0.x, b0.y, b0.z, b0.w, b1.x, b1.y, b1.z, b1.w};
#pragma unroll
      for (int r = 0; r < 8; ++r)
#pragma unroll
        for (int q = 0; q < 8; ++q)
          acc[r][q] += av[r] * bv[q];
    }
  }

  float* __restrict__ out = phi + (size_t)c * M_DIM * M_DIM;
#pragma unroll
  for (int r = 0; r < 8; ++r) {
    const size_t row = (size_t)(px * 32 + tr * 8 + r) * M_DIM;
    const f32x4 o0 = {acc[r][0], acc[r][1], acc[r][2], acc[r][3]};
    const f32x4 o1 = {acc[r][4], acc[r][5], acc[r][6], acc[r][7]};
    __builtin_nontemporal_store(o0, (f32x4*)&out[row + tc * 4]);
    __builtin_nontemporal_store(o1, (f32x4*)&out[row + 256 + tc * 4]);
  }
}

// ---------------------------------------------------------------------------
extern "C" void kernel_launch(void* const* d_in, const int* in_sizes, int n_in,
                              void* d_out, int out_size, void* d_ws,
                              size_t ws_size, hipStream_t stream) {
  const float* X      = (const float*)d_in[0];
  const float* W      = (const float*)d_in[1];
  const int*   labels = (const int*)d_in[2];

  float* out = (float*)d_out;
  float* phi = out;                                // C*M*M
  float* mu  = out + (size_t)C_N * M_DIM * M_DIM;  // C*M
  float* cnt = mu + (size_t)C_N * M_DIM;           // C

  float* part   = (float*)d_ws;                    // 2 x B*M fp32 = 4 MB
  int*   counts = (int*)((char*)d_ws + (size_t)2 * B_N * M_DIM * sizeof(float));
  int*   idx    = counts + 128;                    // C*B ints

  hipLaunchKernelGGL(gemm_index_kernel, dim3(NGEMM + NIDX), dim3(512), 0,
                     stream, X, W, labels, part, counts, idx);
  hipLaunchKernelGGL(phi_mu_kernel, dim3(17, C_N), dim3(256), 0, stream,
                     part, part + (size_t)B_N * M_DIM, counts, idx,
                     phi, mu, cnt);
}

// Round 25
// 38.041 us; speedup vs baseline: 10.4139x; 1.0148x over previous
//
#include <hip/hip_runtime.h>

#define B_N    1024
#define F_DIMC 768
#define M_DIM  512
#define C_N    100
#define KHALF  (F_DIMC / 2)       // 384 per K-split half
#define KSTEP  32
#define NSTEP2 (KHALF / KSTEP)    // 12 k-steps per half
#define NGEMM  256                // 128 tiles (16x8 of 64x64) x 2 K-halves
#define NIDX   13                 // 13 blocks x 8 waves = 104 >= 100 classes

typedef float f32x4 __attribute__((ext_vector_type(4)));
typedef short s16x8 __attribute__((ext_vector_type(8)));

// v_cvt_pk_bf16_f32: dst[15:0] = bf16(lo), dst[31:16] = bf16(hi). RNE.
__device__ __forceinline__ unsigned int cvt_pk_bf16(float lo, float hi) {
  unsigned int r;
  asm("v_cvt_pk_bf16_f32 %0, %1, %2" : "=v"(r) : "v"(lo), "v"(hi));
  return r;
}

// ---------------------------------------------------------------------------
// Kernel 1: MFMA partial gemm (plain bf16 x bf16, fp32 accum), 64x64 tile,
// K-split x2, 512 thr / 8 waves + ballot-rank index build.
// vs R24: Al buffer + lh MFMA dropped (1 MFMA per subtile per k-step).
// Error: fp32-accumulated random-walk of bf16 roundings -> phi ~0.25-0.4.
// ---------------------------------------------------------------------------
__global__ __launch_bounds__(512) void gemm_index_kernel(
    const float* __restrict__ X, const float* __restrict__ W,
    const int* __restrict__ labels, float* __restrict__ part,
    int* __restrict__ counts, int* __restrict__ idx) {
  __shared__ unsigned short Ah[2][64][40];  // [row][k] 80B pitch
  __shared__ unsigned short Bh[2][64][40];  // [col][k] 80B pitch
  __shared__ int lab[B_N];

  const int t = threadIdx.x;
  const int b = (int)blockIdx.x;

  if (b >= NGEMM) {  // ---- index path: one wave per class ----
    for (int i = t; i < B_N; i += 512) lab[i] = labels[i];
    __syncthreads();
    const int w    = t >> 6;
    const int lane = t & 63;
    const int c    = (b - NGEMM) * 8 + w;
    if (c < C_N) {
      int base = 0;
      for (int ch = 0; ch < 16; ++ch) {
        const int j = ch * 64 + lane;
        const bool hit = (lab[j] == c);
        const unsigned long long mask = __ballot(hit);
        if (hit) {
          const int r = __popcll(mask & ((1ull << lane) - 1ull));
          idx[c * B_N + base + r] = j;
        }
        base += __popcll(mask);
      }
      if (lane == 0) counts[c] = base;
    }
    return;
  }

  // ---- MFMA gemm path ----
  const int kb   = b >> 7;          // K-half 0/1
  const int tile = b & 127;         // 0..127
  const int bm = (tile >> 3) * 64;  // 16 row tiles
  const int bn = (tile & 7) * 64;   // 8 col tiles

  // staging roles: threads 0..255 stage X (64r x 32k, 8 f32 each);
  //                threads 256..511 stage W (32k x 64c, 8 f32 each).
  const bool isX = (t < 256);
  const int xr = t >> 2;              // 0..63 row
  const int xk = (t & 3) * 8;         // 0,8,16,24 k-offset
  const int uu = isX ? 0 : (t - 256); // 0..255
  const int wk = (uu >> 4) * 2;       // 0..30 even k
  const int wc = (uu & 15) * 4;       // 0..60 col base

  const float* __restrict__ Xp =
      X + (size_t)(bm + xr) * F_DIMC + kb * KHALF + xk;
  const float* __restrict__ Wp =
      W + (size_t)(kb * KHALF + wk) * M_DIM + bn + wc;

  // compute roles: wave wv owns subtiles (mt, nh*2) and (mt, nh*2+1)
  const int lane = t & 63;
  const int wv   = t >> 6;          // 0..7
  const int m0 = (wv & 3) * 16;     // 4 m-tiles
  const int nh = wv >> 2;           // 0/1 -> n-tiles nh*2, nh*2+1
  const int fr = lane & 15;
  const int fq = (lane >> 4) * 8;

  f32x4 acc0 = {0.f, 0.f, 0.f, 0.f};
  f32x4 acc1 = {0.f, 0.f, 0.f, 0.f};

  float4 ra0, ra1, rb0, rb1;
  if (isX) {
    ra0 = *(const float4*)(Xp);
    ra1 = *(const float4*)(Xp + 4);
  } else {
    rb0 = *(const float4*)(Wp);
    rb1 = *(const float4*)(Wp + M_DIM);
  }

  auto STAGE = [&](int buf) {
    if (isX) {
      const unsigned int h0 = cvt_pk_bf16(ra0.x, ra0.y);
      const unsigned int h1 = cvt_pk_bf16(ra0.z, ra0.w);
      const unsigned int h2 = cvt_pk_bf16(ra1.x, ra1.y);
      const unsigned int h3 = cvt_pk_bf16(ra1.z, ra1.w);
      *(uint4*)&Ah[buf][xr][xk] = make_uint4(h0, h1, h2, h3);
    } else {
      const float a[4] = {rb0.x, rb0.y, rb0.z, rb0.w};   // k = wk
      const float d[4] = {rb1.x, rb1.y, rb1.z, rb1.w};   // k = wk+1
#pragma unroll
      for (int i = 0; i < 4; ++i)
        *(unsigned int*)&Bh[buf][wc + i][wk] = cvt_pk_bf16(a[i], d[i]);
    }
  };

  STAGE(0);
  __syncthreads();

  for (int it = 0; it < NSTEP2; ++it) {
    const int cur = it & 1;
    if (it + 1 < NSTEP2) {
      const int k0 = (it + 1) * KSTEP;
      if (isX) {
        ra0 = *(const float4*)(Xp + k0);
        ra1 = *(const float4*)(Xp + k0 + 4);
      } else {
        rb0 = *(const float4*)(Wp + (size_t)k0 * M_DIM);
        rb1 = *(const float4*)(Wp + (size_t)(k0 + 1) * M_DIM);
      }
    }
    const s16x8 ah = *(const s16x8*)&Ah[cur][m0 + fr][fq];
    {
      const s16x8 bh = *(const s16x8*)&Bh[cur][(nh * 2) * 16 + fr][fq];
      acc0 = __builtin_amdgcn_mfma_f32_16x16x32_bf16(ah, bh, acc0, 0, 0, 0);
    }
    {
      const s16x8 bh = *(const s16x8*)&Bh[cur][(nh * 2 + 1) * 16 + fr][fq];
      acc1 = __builtin_amdgcn_mfma_f32_16x16x32_bf16(ah, bh, acc1, 0, 0, 0);
    }
    if (it + 1 < NSTEP2) STAGE(cur ^ 1);
    __syncthreads();
  }

  // store partials (no relu); C layout: col = lane&15, row = (lane>>4)*4+r
  float* __restrict__ dst = part + (size_t)kb * B_N * M_DIM;
  const int rr0 = (lane >> 4) * 4;
#pragma unroll
  for (int r = 0; r < 4; ++r) {
    const size_t row = (size_t)(bm + m0 + rr0 + r) * M_DIM;
    dst[row + bn + (nh * 2) * 16 + fr]     = acc0[r];
    dst[row + bn + (nh * 2 + 1) * 16 + fr] = acc1[r];
  }
}

// ---------------------------------------------------------------------------
// Kernel 2 (R8/R23/R24 verbatim): phi 32-row panels + mu/count,
// feat = relu(p0+p1) built in staging. grid = (17, C); panel 16 -> mu/count.
// ---------------------------------------------------------------------------
__global__ __launch_bounds__(256, 4) void phi_mu_kernel(
    const float* __restrict__ p0, const float* __restrict__ p1,
    const int* __restrict__ counts, const int* __restrict__ idx,
    float* __restrict__ phi, float* __restrict__ mu,
    float* __restrict__ cnt_out) {
  const int c = blockIdx.y;
  const int n = counts[c];
  const int* __restrict__ id = idx + c * B_N;
  const int t = threadIdx.x;

  if (blockIdx.x == 16) {  // ---- mu / count path ----
    float2 acc = make_float2(0.f, 0.f);
    for (int s = 0; s < n; ++s) {
      const size_t o = (size_t)id[s] * M_DIM + t * 2;
      const float2 q0 = *(const float2*)&p0[o];
      const float2 q1 = *(const float2*)&p1[o];
      acc.x += fmaxf(q0.x + q1.x, 0.f);
      acc.y += fmaxf(q0.y + q1.y, 0.f);
    }
    *(float2*)&mu[(size_t)c * M_DIM + t * 2] = acc;
    if (t == 0) cnt_out[c] = (float)n;
    return;
  }

  // ---- phi row-panel path: rows 32*px..+32, all 512 cols ----
  const int px = (int)blockIdx.x;      // 0..15
  const int tr = t >> 6;               // row group 0..3 (x8 rows)
  const int tc = t & 63;               // cols tc*4 and 256+tc*4

  __shared__ float F[16][M_DIM];

  float acc[8][8] = {};

  for (int s0 = 0; s0 < n; s0 += 16) {
    const int chunk  = min(16, n - s0);
    if (s0) __syncthreads();           // protect F before overwrite
    const int nslots = chunk << 7;     // chunk * 128 float4 per row
    for (int v = t; v < nslots; v += 256) {
      const int sl   = v >> 7;
      const int fp   = (v & 127) << 2;
      const size_t o = (size_t)id[s0 + sl] * M_DIM + fp;
      const float4 q0 = *(const float4*)&p0[o];
      const float4 q1 = *(const float4*)&p1[o];
      float4 f;
      f.x = fmaxf(q0.x + q1.x, 0.f);
      f.y = fmaxf(q0.y + q1.y, 0.f);
      f.z = fmaxf(q0.z + q1.z, 0.f);
      f.w = fmaxf(q0.w + q1.w, 0.f);
      *(float4*)&F[sl][fp] = f;
    }
    __syncthreads();
    for (int sl = 0; sl < chunk; ++sl) {
      const float4 a0 = *(const float4*)&F[sl][px * 32 + tr * 8];      // bcast
      const float4 a1 = *(const float4*)&F[sl][px * 32 + tr * 8 + 4];  // bcast
      const float4 b0 = *(const float4*)&F[sl][tc * 4];        // contiguous
      const float4 b1 = *(const float4*)&F[sl][256 + tc * 4];  // contiguous
      const float av[8] = {a0.x, a0.y, a0.z, a0.w, a1.x, a1.y, a1.z, a1.w};
      const float bv[8] = {b0.x, b0.y, b0.z, b0.w, b1.x, b1.y, b1.z, b1.w};
#pragma unroll
      for (int r = 0; r < 8; ++r)
#pragma unroll
        for (int q = 0; q < 8; ++q)
          acc[r][q] += av[r] * bv[q];
    }
  }

  float* __restrict__ out = phi + (size_t)c * M_DIM * M_DIM;
#pragma unroll
  for (int r = 0; r < 8; ++r) {
    const size_t row = (size_t)(px * 32 + tr * 8 + r) * M_DIM;
    const f32x4 o0 = {acc[r][0], acc[r][1], acc[r][2], acc[r][3]};
    const f32x4 o1 = {acc[r][4], acc[r][5], acc[r][6], acc[r][7]};
    __builtin_nontemporal_store(o0, (f32x4*)&out[row + tc * 4]);
    __builtin_nontemporal_store(o1, (f32x4*)&out[row + 256 + tc * 4]);
  }
}

// ---------------------------------------------------------------------------
extern "C" void kernel_launch(void* const* d_in, const int* in_sizes, int n_in,
                              void* d_out, int out_size, void* d_ws,
                              size_t ws_size, hipStream_t stream) {
  const float* X      = (const float*)d_in[0];
  const float* W      = (const float*)d_in[1];
  const int*   labels = (const int*)d_in[2];

  float* out = (float*)d_out;
  float* phi = out;                                // C*M*M
  float* mu  = out + (size_t)C_N * M_DIM * M_DIM;  // C*M
  float* cnt = mu + (size_t)C_N * M_DIM;           // C

  float* part   = (float*)d_ws;                    // 2 x B*M fp32 = 4 MB
  int*   counts = (int*)((char*)d_ws + (size_t)2 * B_N * M_DIM * sizeof(float));
  int*   idx    = counts + 128;                    // C*B ints

  hipLaunchKernelGGL(gemm_index_kernel, dim3(NGEMM + NIDX), dim3(512), 0,
                     stream, X, W, labels, part, counts, idx);
  hipLaunchKernelGGL(phi_mu_kernel, dim3(17, C_N), dim3(256), 0, stream,
                     part, part + (size_t)B_N * M_DIM, counts, idx,
                     phi, mu, cnt);
}